// Round 1
// baseline (3722.945 us; speedup 1.0000x reference)
//
#include <hip/hip_runtime.h>
#include <hip/hip_bf16.h>

#define N_NODES 100000
#define D_IN 128
#define D_H 256
#define D_E 64
#define NB 4  // nodes per block in GEMM-ish kernels

// ---------------- scatter kernels ----------------

__global__ void deg_kernel(const int* __restrict__ dst, float* __restrict__ deg, int E) {
    int e = blockIdx.x * blockDim.x + threadIdx.x;
    if (e >= E) return;
    atomicAdd(&deg[dst[e]], 1.0f);
}

// one thread per (edge, feature), feature dim 128
__global__ void scatter_x_kernel(const float* __restrict__ x,
                                 const int* __restrict__ src,
                                 const int* __restrict__ dst,
                                 float* __restrict__ agg, long long total) {
    long long gid = (long long)blockIdx.x * blockDim.x + threadIdx.x;
    if (gid >= total) return;
    int e = (int)(gid >> 7);
    int f = (int)(gid & 127);
    int s = src[e], d = dst[e];
    atomicAdd(&agg[(long long)d * D_IN + f], x[(long long)s * D_IN + f]);
}

// one thread per (edge, feature), feature dim 64
__global__ void scatter_z_kernel(const float* __restrict__ z,
                                 const int* __restrict__ src,
                                 const int* __restrict__ dst,
                                 float* __restrict__ agg, long long total) {
    long long gid = (long long)blockIdx.x * blockDim.x + threadIdx.x;
    if (gid >= total) return;
    int e = (int)(gid >> 6);
    int f = (int)(gid & 63);
    int s = src[e], d = dst[e];
    atomicAdd(&agg[(long long)d * D_E + f], z[(long long)s * D_E + f]);
}

// ---------------- fused layer-1 + layer-2 input transforms ----------------
// per node: mean = agg1/deg; h = relu(W_l1*mean + b_l1 + W_r1*x);
//           z2 = W_l2*h   (to be scattered);  r2 = W_r2*h  (self term)
__global__ __launch_bounds__(256) void layer1_kernel(
        const float* __restrict__ x, const float* __restrict__ agg1,
        const float* __restrict__ deg,
        const float* __restrict__ Wl1, const float* __restrict__ bl1,
        const float* __restrict__ Wr1,
        const float* __restrict__ Wl2, const float* __restrict__ Wr2,
        float* __restrict__ z2, float* __restrict__ r2) {
    __shared__ float smean[NB][D_IN];
    __shared__ float sx[NB][D_IN];
    __shared__ float sh[NB][D_H];
    const int node0 = blockIdx.x * NB;
    const int tid = threadIdx.x;

    for (int i = tid; i < NB * D_IN; i += 256) {
        int nb = i >> 7, f = i & 127;
        int n = node0 + nb;
        float dv = fmaxf(deg[n], 1.0f);
        smean[nb][f] = agg1[(long long)n * D_IN + f] / dv;
        sx[nb][f] = x[(long long)n * D_IN + f];
    }
    __syncthreads();

    // h[tid] for NB nodes
    float acc[NB];
    float bv = bl1[tid];
#pragma unroll
    for (int nb = 0; nb < NB; nb++) acc[nb] = bv;
    const float* wl = Wl1 + (long long)tid * D_IN;
    const float* wr = Wr1 + (long long)tid * D_IN;
    for (int f = 0; f < D_IN; f++) {
        float wlv = wl[f], wrv = wr[f];
#pragma unroll
        for (int nb = 0; nb < NB; nb++)
            acc[nb] += wlv * smean[nb][f] + wrv * sx[nb][f];
    }
#pragma unroll
    for (int nb = 0; nb < NB; nb++) sh[nb][tid] = fmaxf(acc[nb], 0.0f);
    __syncthreads();

    // z2 / r2: 64 outputs each, dot over 256
    if (tid < 128) {
        int o = tid & 63;
        const float* w = (tid < 64) ? (Wl2 + (long long)o * D_H)
                                    : (Wr2 + (long long)o * D_H);
        float a2[NB];
#pragma unroll
        for (int nb = 0; nb < NB; nb++) a2[nb] = 0.0f;
        for (int k = 0; k < D_H; k++) {
            float wv = w[k];
#pragma unroll
            for (int nb = 0; nb < NB; nb++) a2[nb] += wv * sh[nb][k];
        }
        float* outp = (tid < 64) ? z2 : r2;
#pragma unroll
        for (int nb = 0; nb < NB; nb++)
            outp[(long long)(node0 + nb) * D_E + o] = a2[nb];
    }
}

// emb = aggz/deg + b_l2 + r2   (written straight to d_out)
__global__ void emb_kernel(const float* __restrict__ aggz,
                           const float* __restrict__ deg,
                           const float* __restrict__ bl2,
                           const float* __restrict__ r2,
                           float* __restrict__ emb, int total) {
    int gid = blockIdx.x * blockDim.x + threadIdx.x;
    if (gid >= total) return;
    int n = gid >> 6, f = gid & 63;
    float dv = fmaxf(deg[n], 1.0f);
    emb[gid] = aggz[gid] / dv + bl2[f] + r2[gid];
}

// decoder fused: hid = relu(fc1_W*emb + fc1_b) in LDS; recon = fc2_W*hid + fc2_b
__global__ __launch_bounds__(256) void decoder_kernel(
        const float* __restrict__ emb,
        const float* __restrict__ fc1W, const float* __restrict__ fc1b,
        const float* __restrict__ fc2W, const float* __restrict__ fc2b,
        float* __restrict__ recon) {
    __shared__ float se[NB][D_E];
    __shared__ float sh[NB][D_H];
    const int node0 = blockIdx.x * NB;
    const int tid = threadIdx.x;

    {
        int nb = tid >> 6, f = tid & 63;  // 256 threads cover NB*64 exactly
        se[nb][f] = emb[(long long)(node0 + nb) * D_E + f];
    }
    __syncthreads();

    float acc[NB];
    float bv = fc1b[tid];
#pragma unroll
    for (int nb = 0; nb < NB; nb++) acc[nb] = bv;
    const float* w = fc1W + (long long)tid * D_E;
    for (int k = 0; k < D_E; k++) {
        float wv = w[k];
#pragma unroll
        for (int nb = 0; nb < NB; nb++) acc[nb] += wv * se[nb][k];
    }
#pragma unroll
    for (int nb = 0; nb < NB; nb++) sh[nb][tid] = fmaxf(acc[nb], 0.0f);
    __syncthreads();

    if (tid < D_IN) {
        float a2[NB];
        float b2 = fc2b[tid];
#pragma unroll
        for (int nb = 0; nb < NB; nb++) a2[nb] = b2;
        const float* w2 = fc2W + (long long)tid * D_H;
        for (int k = 0; k < D_H; k++) {
            float wv = w2[k];
#pragma unroll
            for (int nb = 0; nb < NB; nb++) a2[nb] += wv * sh[nb][k];
        }
#pragma unroll
        for (int nb = 0; nb < NB; nb++)
            recon[(long long)(node0 + nb) * D_IN + tid] = a2[nb];
    }
}

extern "C" void kernel_launch(void* const* d_in, const int* in_sizes, int n_in,
                              void* d_out, int out_size, void* d_ws, size_t ws_size,
                              hipStream_t stream) {
    const float* x    = (const float*)d_in[0];
    const int*   ei   = (const int*)d_in[1];
    const int E = in_sizes[1] / 2;
    const int* src = ei;
    const int* dst = ei + E;
    const float* Wl1  = (const float*)d_in[2];
    const float* bl1  = (const float*)d_in[3];
    const float* Wr1  = (const float*)d_in[4];
    const float* Wl2  = (const float*)d_in[5];
    const float* bl2  = (const float*)d_in[6];
    const float* Wr2  = (const float*)d_in[7];
    const float* fc1W = (const float*)d_in[8];
    const float* fc1b = (const float*)d_in[9];
    const float* fc2W = (const float*)d_in[10];
    const float* fc2b = (const float*)d_in[11];

    float* out   = (float*)d_out;
    float* emb   = out;                                  // N*64
    float* recon = out + (size_t)N_NODES * D_E;          // N*128

    // workspace layout (16B-aligned offsets)
    char* ws = (char*)d_ws;
    float* agg1 = (float*)(ws);                  // N*128*4 = 51,200,000 B
    float* z2   = (float*)(ws + 51200000);       // N*64*4  = 25,600,000 B
    float* aggz = (float*)(ws + 76800000);       // N*64*4
    float* r2   = (float*)(ws + 102400000);      // N*64*4
    float* deg  = (float*)(ws + 128000000);      // N*4 = 400,000 B
    // total: 128,400,000 B

    hipMemsetAsync(agg1, 0, (size_t)N_NODES * D_IN * sizeof(float), stream);
    hipMemsetAsync(aggz, 0, (size_t)N_NODES * D_E * sizeof(float), stream);
    hipMemsetAsync(deg,  0, (size_t)N_NODES * sizeof(float), stream);

    deg_kernel<<<(E + 255) / 256, 256, 0, stream>>>(dst, deg, E);

    long long tot1 = (long long)E * D_IN;
    scatter_x_kernel<<<(int)((tot1 + 255) / 256), 256, 0, stream>>>(x, src, dst, agg1, tot1);

    layer1_kernel<<<N_NODES / NB, 256, 0, stream>>>(x, agg1, deg, Wl1, bl1, Wr1,
                                                    Wl2, Wr2, z2, r2);

    long long tot2 = (long long)E * D_E;
    scatter_z_kernel<<<(int)((tot2 + 255) / 256), 256, 0, stream>>>(z2, src, dst, aggz, tot2);

    emb_kernel<<<(N_NODES * D_E + 255) / 256, 256, 0, stream>>>(aggz, deg, bl2, r2,
                                                                emb, N_NODES * D_E);

    decoder_kernel<<<N_NODES / NB, 256, 0, stream>>>(emb, fc1W, fc1b, fc2W, fc2b, recon);
}